// Round 4
// baseline (467.436 us; speedup 1.0000x reference)
//
#include <hip/hip_runtime.h>

// Gaussian blur over ALL axes of (32,3,512,512) f32, sigma = k_size = 5,
// radius = 20, 41 taps, 'symmetric' (scipy reflect) edges.
// pass1 = axis3 (rows, direct-global sliding window, no LDS)
// pass2 = axis2 (cols, LDS tile, float4 staging, conflict-free)
// pass3 = axes 0+1 fused via folded reflection weight matrices.

#define R     20
#define TAPS  41
#define NB    32
#define CB    3
#define HH    512
#define WW    512
#define PLANE (HH * WW)

#define NROWS (NB * CB * HH)          // 49152 rows for pass1
#define IGRP  58                      // interior output groups per row (g=3..60)
#define EGRP  6                       // edge groups per row (0,1,2,61,62,63)
#define IBLOCKS ((NROWS * IGRP) / 256)   // 11136
#define EBLOCKS ((NROWS * EGRP) / 256)   // 1152

__device__ float g_w[TAPS];
__device__ float g_W0[NB * NB];  // folded weights along axis 0 (L=32)
__device__ float g_W1[CB * CB];  // folded weights along axis 1 (L=3)

__device__ __forceinline__ int foldi(int i, int L) {
    int p = 2 * L;
    int j = i % p;
    if (j < 0) j += p;
    return (j < L) ? j : (p - 1 - j);
}

__global__ void init_weights(const int* __restrict__ k_size) {
    __shared__ float w[TAPS];
    __shared__ float s_inv;
    int tid = threadIdx.x;  // 64 threads
    float sigma = (float)k_size[0];
    if (tid < TAPS) {
        float x = (float)(tid - R) / sigma;
        w[tid] = expf(-0.5f * x * x);
    }
    __syncthreads();
    if (tid == 0) {
        float s = 0.f;
        for (int t = 0; t < TAPS; ++t) s += w[t];
        s_inv = 1.f / s;
    }
    __syncthreads();
    if (tid < TAPS) {
        w[tid] *= s_inv;
        g_w[tid] = w[tid];
    }
    __syncthreads();
    for (int e = tid; e < NB * NB; e += 64) {
        int o = e >> 5, i = e & 31;
        float s = 0.f;
        for (int t = 0; t < TAPS; ++t)
            if (foldi(o + t - R, NB) == i) s += w[t];
        g_W0[e] = s;
    }
    for (int e = tid; e < CB * CB; e += 64) {
        int o = e / 3, i = e % 3;
        float s = 0.f;
        for (int t = 0; t < TAPS; ++t)
            if (foldi(o + t - R, CB) == i) s += w[t];
        g_W1[e] = s;
    }
}

// ---- Pass 1: blur along axis 3. Direct-global register sliding window. ----
// Interior blocks: thread -> (row, group g in [3,60]), 8 outputs, window of 48
// floats starting at 8g-20 (16B-aligned) = 12 float4 loads.
// Edge blocks: groups {0,1,2,61,62,63}, scalar folded loads.
__global__ __launch_bounds__(256) void blur_w_kernel(
        const float* __restrict__ in, float* __restrict__ out) {
    int bid = blockIdx.x;
    float buf[48];
    long long rowIdx;
    int g;
    if (bid < IBLOCKS) {
        int G = bid * 256 + threadIdx.x;      // < 49152*58
        int row = G / IGRP;
        g = G - row * IGRP + 3;               // 3..60
        rowIdx = row;
        const float* src = in + rowIdx * WW + (8 * g - R);
#pragma unroll
        for (int q = 0; q < 12; ++q) {
            float4 v = *(const float4*)(src + 4 * q);
            buf[4 * q + 0] = v.x; buf[4 * q + 1] = v.y;
            buf[4 * q + 2] = v.z; buf[4 * q + 3] = v.w;
        }
    } else {
        int E = (bid - IBLOCKS) * 256 + threadIdx.x;  // < 49152*6
        int row = E / EGRP;
        int j = E - row * EGRP;
        g = (j < 3) ? j : (j + 58);           // {0,1,2,61,62,63}
        rowIdx = row;
        const float* src = in + rowIdx * WW;
#pragma unroll
        for (int i = 0; i < 48; ++i)
            buf[i] = src[foldi(8 * g - R + i, WW)];
    }

    float o[8];
#pragma unroll
    for (int k = 0; k < 8; ++k) {
        float a = 0.f;
#pragma unroll
        for (int t = 0; t < TAPS; ++t) a = fmaf(g_w[t], buf[k + t], a);
        o[k] = a;
    }
    float* dst = out + rowIdx * WW + 8 * g;
    *(float4*)(dst + 0) = make_float4(o[0], o[1], o[2], o[3]);
    *(float4*)(dst + 4) = make_float4(o[4], o[5], o[6], o[7]);
}

// ---- Pass 2: blur along axis 2 (stride 512). ----
// Tile 64 cols x 64 out rows; float4 staging into padded LDS (68 f/row);
// compute reads are lane-stride-1 (conflict-free). 16 outputs/thread.
__global__ __launch_bounds__(256) void blur_h_kernel(
        const float* __restrict__ in, float* __restrict__ out) {
    __shared__ float tile[64 + 2 * R][68];  // pad 64->68: staggers b128 writes
    int tid = threadIdx.x;
    int x0 = blockIdx.x * 64;
    int y0 = blockIdx.y * 64;
    long long plane = blockIdx.z;  // 0..95
    const float* src = in + plane * PLANE + x0;

    // stage 104 rows x 16 float4
#pragma unroll
    for (int k = 0; k < 7; ++k) {
        int e = tid + k * 256;
        if (e < 104 * 16) {
            int row = e >> 4, q = e & 15;
            float4 v = *(const float4*)(src + (long long)foldi(y0 - R + row, HH) * WW + 4 * q);
            *(float4*)&tile[row][4 * q] = v;
        }
    }
    __syncthreads();

    int tx = tid & 63;
    int yb = (tid >> 6) * 16;
    float buf[16 + 2 * R];
#pragma unroll
    for (int i = 0; i < 16 + 2 * R; ++i) buf[i] = tile[yb + i][tx];

    float* dst = out + plane * PLANE + (long long)(y0 + yb) * WW + x0 + tx;
#pragma unroll
    for (int k = 0; k < 16; ++k) {
        float a = 0.f;
#pragma unroll
        for (int t = 0; t < TAPS; ++t) a = fmaf(g_w[t], buf[k + t], a);
        dst[(long long)k * WW] = a;
    }
}

// ---- Pass 3: fused blur along axes 0 (L=32) and 1 (L=3). ----
__global__ __launch_bounds__(256) void blur_nc_kernel(
        const float* __restrict__ in, float* __restrict__ out) {
    int p = blockIdx.x * 256 + threadIdx.x;
    const float* src = in + p;

    float tmp[NB][CB];
#pragma unroll
    for (int n2 = 0; n2 < NB; ++n2) {
        float v0 = src[(n2 * 3 + 0) * PLANE];
        float v1 = src[(n2 * 3 + 1) * PLANE];
        float v2 = src[(n2 * 3 + 2) * PLANE];
        tmp[n2][0] = fmaf(g_W1[0], v0, fmaf(g_W1[1], v1, g_W1[2] * v2));
        tmp[n2][1] = fmaf(g_W1[3], v0, fmaf(g_W1[4], v1, g_W1[5] * v2));
        tmp[n2][2] = fmaf(g_W1[6], v0, fmaf(g_W1[7], v1, g_W1[8] * v2));
    }
    for (int n = 0; n < NB; ++n) {
        float a0 = 0.f, a1 = 0.f, a2 = 0.f;
#pragma unroll
        for (int n2 = 0; n2 < NB; ++n2) {
            float wv = g_W0[n * NB + n2];
            a0 = fmaf(wv, tmp[n2][0], a0);
            a1 = fmaf(wv, tmp[n2][1], a1);
            a2 = fmaf(wv, tmp[n2][2], a2);
        }
        out[(n * 3 + 0) * PLANE + p] = a0;
        out[(n * 3 + 1) * PLANE + p] = a1;
        out[(n * 3 + 2) * PLANE + p] = a2;
    }
}

extern "C" void kernel_launch(void* const* d_in, const int* in_sizes, int n_in,
                              void* d_out, int out_size, void* d_ws, size_t ws_size,
                              hipStream_t stream) {
    const float* x  = (const float*)d_in[0];
    const int*   ks = (const int*)d_in[1];
    float* out = (float*)d_out;
    float* tmp = (float*)d_ws;  // NB*CB*PLANE floats = 100.7 MB

    init_weights<<<1, 64, 0, stream>>>(ks);
    blur_w_kernel<<<IBLOCKS + EBLOCKS, 256, 0, stream>>>(x, out);
    blur_h_kernel<<<dim3(WW / 64, HH / 64, NB * CB), dim3(256), 0, stream>>>(out, tmp);
    blur_nc_kernel<<<PLANE / 256, 256, 0, stream>>>(tmp, out);
}

// Round 9
// 287.726 us; speedup vs baseline: 1.6246x; 1.6246x over previous
//
#include <hip/hip_runtime.h>

// Gaussian blur over ALL axes of (32,3,512,512) f32, sigma = k_size = 5,
// radius = 20, 41 taps, 'symmetric' edges. STATELESS + ZERO-WORKSPACE:
//   k1 blur_h : axis 2 (columns), x -> out        (out-of-place)
//   k2 blur_w : axis 3 (rows),    out -> out      (in-place, per-row waves)
//   k3 blur_nc: axes 0+1 fused,   out -> out      (in-place, per-pixel)
// No __device__ globals, no d_ws usage: every kernel derives its weights
// per block in LDS from k_size. Nothing persists across calls.

#define R     20
#define TAPS  41
#define NB    32
#define CB    3
#define HH    512
#define WW    512
#define PLANE (HH * WW)
#define NROWS (NB * CB * HH)     // 49152
#define PADW  (WW + 2 * R)       // 552
#define PADS  624                // > 551 + 551/8

__device__ __forceinline__ int foldi(int i, int L) {
    int p = 2 * L;
    int j = i % p;
    if (j < 0) j += p;
    return (j < L) ? j : (p - 1 - j);
}

// Normalized gaussian taps into LDS sw[TAPS]. Call with all threads; contains
// two block barriers.
__device__ __forceinline__ void make_weights(float* sw, float sigma, int tid) {
    if (tid < TAPS) {
        float x = (float)(tid - R) / sigma;
        sw[tid] = expf(-0.5f * x * x);
    }
    __syncthreads();
    if (tid == 0) {
        float s = 0.f;
        for (int t = 0; t < TAPS; ++t) s += sw[t];
        float inv = 1.f / s;
        for (int t = 0; t < TAPS; ++t) sw[t] *= inv;
    }
    __syncthreads();
}

// ---- k1: blur along axis 2 (stride 512), x -> out. ----
// Tile 64 cols x 128 out rows, 512 threads, 16 outputs/thread, f4 staging.
__global__ __launch_bounds__(512) void blur_h_kernel(
        const float* __restrict__ in, float* __restrict__ out,
        const int* __restrict__ ks) {
    __shared__ float tile[128 + 2 * R][68];
    __shared__ float sw[TAPS];
    int tid = threadIdx.x;
    make_weights(sw, (float)ks[0], tid);

    int x0 = blockIdx.x * 64;
    int y0 = blockIdx.y * 128;
    long long plane = blockIdx.z;  // 0..95
    const float* src = in + plane * PLANE + x0;

#pragma unroll
    for (int k = 0; k < 6; ++k) {
        int e = tid + k * 512;
        if (e < 168 * 16) {
            int row = e >> 4, q = e & 15;
            *(float4*)&tile[row][4 * q] =
                *(const float4*)(src + (long long)foldi(y0 - R + row, HH) * WW + 4 * q);
        }
    }
    __syncthreads();

    int tx = tid & 63;
    int yb = (tid >> 6) * 16;   // 0..112
    float buf[16 + 2 * R];
#pragma unroll
    for (int i = 0; i < 16 + 2 * R; ++i) buf[i] = tile[yb + i][tx];

    float* dst = out + plane * PLANE + (long long)(y0 + yb) * WW + x0 + tx;
#pragma unroll
    for (int k = 0; k < 16; ++k) {
        float a = 0.f;
#pragma unroll
        for (int t = 0; t < TAPS; ++t) a = fmaf(sw[t], buf[k + t], a);
        dst[(long long)k * WW] = a;
    }
}

// ---- k2: blur along axis 3 (rows), IN-PLACE. ----
// 4 rows/block, one per wave. A wave stages its ENTIRE row (halo folds stay
// within the row) into LDS before any write-back -> in-place safe.
// Stride-9 padded layout: element i at word i + i/8; reads at lane-stride 9
// words (gcd(9,32)=1 -> 2 lanes/bank, free), offsets fold into immediates.
__global__ __launch_bounds__(256) void blur_w_kernel(float* data,
        const int* __restrict__ ks) {
    __shared__ float rowp[4][PADS];
    __shared__ float sw[TAPS];
    int tid  = threadIdx.x;
    make_weights(sw, (float)ks[0], tid);

    int lrow = tid >> 6;
    int lc   = tid & 63;
    long long rowIdx = (long long)blockIdx.x * 4 + lrow;
    float* src = data + rowIdx * WW;

    for (int i = lc; i < PADW; i += 64)
        rowp[lrow][i + (i >> 3)] = src[foldi(i - R, WW)];
    __syncthreads();

    const float* rp = &rowp[lrow][9 * lc];
    float buf[48];
#pragma unroll
    for (int c = 0; c < 48; ++c)
        buf[c] = rp[c + (c >> 3)];   // compile-time offsets

    float o[8];
#pragma unroll
    for (int k = 0; k < 8; ++k) {
        float a = 0.f;
#pragma unroll
        for (int t = 0; t < TAPS; ++t) a = fmaf(sw[t], buf[k + t], a);
        o[k] = a;
    }
    float* dst = src + 8 * lc;
    *(float4*)(dst + 0) = make_float4(o[0], o[1], o[2], o[3]);
    *(float4*)(dst + 4) = make_float4(o[4], o[5], o[6], o[7]);
}

// ---- k3: fused blur along axes 0 (L=32) and 1 (L=3), IN-PLACE. ----
// Folded reflect matrices computed per block in LDS. Thread p loads all 96
// (n,c) values into registers, then writes the same 96 addresses. `data` is
// deliberately NOT __restrict__: loads and stores alias, program order holds.
__global__ __launch_bounds__(256) void blur_nc_kernel(float* data,
        const int* __restrict__ ks) {
    __shared__ float sw[TAPS];
    __shared__ float W0[NB * NB];
    __shared__ float W1[CB * CB];
    int tid = threadIdx.x;
    make_weights(sw, (float)ks[0], tid);

    for (int e = tid; e < NB * NB; e += 256) {
        int o = e >> 5, i = e & 31;
        float s = 0.f;
        for (int t = 0; t < TAPS; ++t)
            if (foldi(o + t - R, NB) == i) s += sw[t];
        W0[e] = s;
    }
    if (tid < CB * CB) {
        int o = tid / 3, i = tid % 3;
        float s = 0.f;
        for (int t = 0; t < TAPS; ++t)
            if (foldi(o + t - R, CB) == i) s += sw[t];
        W1[tid] = s;
    }
    __syncthreads();

    int p = blockIdx.x * 256 + tid;
    float* src = data + p;

    float tmp[NB][CB];
#pragma unroll
    for (int n2 = 0; n2 < NB; ++n2) {
        float v0 = src[(n2 * 3 + 0) * PLANE];
        float v1 = src[(n2 * 3 + 1) * PLANE];
        float v2 = src[(n2 * 3 + 2) * PLANE];
        tmp[n2][0] = fmaf(W1[0], v0, fmaf(W1[1], v1, W1[2] * v2));
        tmp[n2][1] = fmaf(W1[3], v0, fmaf(W1[4], v1, W1[5] * v2));
        tmp[n2][2] = fmaf(W1[6], v0, fmaf(W1[7], v1, W1[8] * v2));
    }
    for (int n = 0; n < NB; ++n) {
        float a0 = 0.f, a1 = 0.f, a2 = 0.f;
#pragma unroll
        for (int n2 = 0; n2 < NB; ++n2) {
            float wv = W0[n * NB + n2];
            a0 = fmaf(wv, tmp[n2][0], a0);
            a1 = fmaf(wv, tmp[n2][1], a1);
            a2 = fmaf(wv, tmp[n2][2], a2);
        }
        src[(n * 3 + 0) * PLANE] = a0;
        src[(n * 3 + 1) * PLANE] = a1;
        src[(n * 3 + 2) * PLANE] = a2;
    }
}

extern "C" void kernel_launch(void* const* d_in, const int* in_sizes, int n_in,
                              void* d_out, int out_size, void* d_ws, size_t ws_size,
                              hipStream_t stream) {
    const float* x  = (const float*)d_in[0];
    const int*   ks = (const int*)d_in[1];
    float* out = (float*)d_out;
    (void)d_ws; (void)ws_size;  // deliberately unused

    blur_h_kernel<<<dim3(WW / 64, HH / 128, NB * CB), dim3(512), 0, stream>>>(x, out, ks);
    blur_w_kernel<<<NROWS / 4, 256, 0, stream>>>(out, ks);
    blur_nc_kernel<<<PLANE / 256, 256, 0, stream>>>(out, ks);
}